// Round 5
// baseline (920.554 us; speedup 1.0000x reference)
//
#include <hip/hip_runtime.h>
#include <math.h>

#define B_ 4
#define N_ 4096
#define C_ 1024
#define H_ 16
#define D_ 64
#define M_ (B_*N_)      // 16384 rows
#define GK 1024         // GEMM K dim (both GEMMs)
#define NCH 8           // N-chunks for kv partial reduction
#define CHROWS (N_/NCH) // 512

typedef __attribute__((ext_vector_type(8))) _Float16 f16x8;
typedef __attribute__((ext_vector_type(4))) _Float16 f16x4;
typedef __attribute__((ext_vector_type(4))) float f32x4;

__device__ __forceinline__ float phi_f(float t) {
  return (t > 0.0f) ? (t + 1.0f) : __expf(t);
}

__device__ __forceinline__ f32x4 mfma16h(f16x8 a, f16x8 b, f32x4 c) {
  return __builtin_amdgcn_mfma_f32_16x16x32_f16(a, b, c, 0, 0, 0);
}

// ---------------- mask dtype detection ----------------
__global__ __launch_bounds__(256) void mask_detect_k(const unsigned int* __restrict__ w,
                                                     int* __restrict__ flag) {
  __shared__ int notint, notflt;
  if (threadIdx.x == 0) { notint = 0; notflt = 0; }
  __syncthreads();
  int ni = 0, nf = 0;
  for (int i = threadIdx.x; i < 4096; i += 256) {
    unsigned int v = w[i];
    if (v > 1u) ni = 1;
    if (v != 0u && v != 0x3F800000u) nf = 1;
  }
  if (ni) atomicOr(&notint, 1);
  if (nf) atomicOr(&notflt, 1);
  __syncthreads();
  if (threadIdx.x == 0) *flag = (!notint) ? 0 : ((!notflt) ? 1 : 2);
}

__global__ __launch_bounds__(256) void mask_convert_k(const void* __restrict__ mask,
                                                      const int* __restrict__ flag,
                                                      float* __restrict__ valid) {
  int i = blockIdx.x * 256 + threadIdx.x;  // 16384 total
  int f = *flag;
  int m;
  if (f == 0)      m = ((const int*)mask)[i] != 0;
  else if (f == 1) m = ((const float*)mask)[i] != 0.0f;
  else             m = ((const unsigned char*)mask)[i] != 0;
  valid[i] = m ? 0.0f : 1.0f;  // True = PAD -> 0
}

// ---------------- fp32 -> fp16 single convert (x4) ----------------
__global__ __launch_bounds__(256) void conv_f16_k(const float* __restrict__ src,
                                                  _Float16* __restrict__ dst, int n4) {
  int i = blockIdx.x * 256 + threadIdx.x;
  if (i >= n4) return;
  float4 v = ((const float4*)src)[i];
  f16x4 h;
  h[0] = (_Float16)v.x; h[1] = (_Float16)v.y;
  h[2] = (_Float16)v.z; h[3] = (_Float16)v.w;
  ((f16x4*)dst)[i] = h;
}

// ---------------- fp32 -> fp16 hi/lo split (x4) ----------------
__global__ __launch_bounds__(256) void split_f16_k(const float* __restrict__ src,
                                                   _Float16* __restrict__ h,
                                                   _Float16* __restrict__ l, int n4) {
  int i = blockIdx.x * 256 + threadIdx.x;
  if (i >= n4) return;
  float4 v = ((const float4*)src)[i];
  f16x4 hv, lv;
  float vs[4] = {v.x, v.y, v.z, v.w};
#pragma unroll
  for (int q = 0; q < 4; ++q) {
    _Float16 hh = (_Float16)vs[q];
    _Float16 ll = (_Float16)(vs[q] - (float)hh);
    hv[q] = hh; lv[q] = ll;
  }
  ((f16x4*)h)[i] = hv;
  ((f16x4*)l)[i] = lv;
}

// ---------------- no-LDS register-pipelined fp16 MFMA GEMM ----------------
// out[m][j] = sum_k A[m][k]*(Bh+Bl)[j][k].  128x128 block, 4 waves (2x2), each
// wave owns 64x64 via 4x4 of 16x16x32 MFMA.  A/B fragments loaded DIRECTLY
// global->VGPR in MFMA layout (lane: row=L&15, k=(L>>4)*8, 16B/lane), no LDS,
// no barriers; depth-1 register double-buffer (ping-pong by unroll-2) gives
// the compiler natural fine-grained vmcnt scheduling.
// EPI 0: qkv epilogue (bias + phi/mask -> [B,H,N,D] fp16); EPI 1: bias + fp32 row-major.
template <int EPI>
__global__ __launch_bounds__(256) void gemm_f16_k(
    const _Float16* __restrict__ A,
    const _Float16* __restrict__ Bh, const _Float16* __restrict__ Bl,
    const float* __restrict__ bias, const float* __restrict__ valid,
    _Float16* __restrict__ qf, _Float16* __restrict__ kf, _Float16* __restrict__ vv,
    float* __restrict__ outp, int jb) {
  const int tid = threadIdx.x;
  const int lane = tid & 63, w = tid >> 6;
  const int lm = lane & 15, lq = lane >> 4;
  const int wm = w >> 1, wj = w & 1;
  const int m0 = blockIdx.x * 128;
  const int jg0 = jb + blockIdx.y * 128;
  const _Float16* pA  = A  + (size_t)(m0  + wm * 64 + lm) * GK + lq * 8;
  const _Float16* pBh = Bh + (size_t)(jg0 + wj * 64 + lm) * GK + lq * 8;
  const _Float16* pBl = Bl + (size_t)(jg0 + wj * 64 + lm) * GK + lq * 8;

  f16x8 a0[4], h0[4], l0[4], a1[4], h1[4], l1[4];
#pragma unroll
  for (int i = 0; i < 4; ++i) {
    size_t ro = (size_t)i * 16 * GK;
    a0[i] = *(const f16x8*)(pA  + ro);
    h0[i] = *(const f16x8*)(pBh + ro);
    l0[i] = *(const f16x8*)(pBl + ro);
  }
  f32x4 acc[4][4] = {};
#pragma unroll 1
  for (int k0 = 0; k0 < GK; k0 += 64) {
    // prefetch stage1 <- k0+32 (always valid: k0+32 <= GK-32)
#pragma unroll
    for (int i = 0; i < 4; ++i) {
      size_t ro = (size_t)i * 16 * GK + k0 + 32;
      a1[i] = *(const f16x8*)(pA  + ro);
      h1[i] = *(const f16x8*)(pBh + ro);
      l1[i] = *(const f16x8*)(pBl + ro);
    }
    // compute stage0
#pragma unroll
    for (int i = 0; i < 4; ++i)
#pragma unroll
      for (int j = 0; j < 4; ++j) {
        acc[i][j] = mfma16h(a0[i], h1 == h1 ? h0[j] : h0[j], acc[i][j]);
        acc[i][j] = mfma16h(a0[i], l0[j], acc[i][j]);
      }
    // prefetch stage0 <- k0+64 (skip on last iter)
    if (k0 + 64 < GK) {
#pragma unroll
      for (int i = 0; i < 4; ++i) {
        size_t ro = (size_t)i * 16 * GK + k0 + 64;
        a0[i] = *(const f16x8*)(pA  + ro);
        h0[i] = *(const f16x8*)(pBh + ro);
        l0[i] = *(const f16x8*)(pBl + ro);
      }
    }
    // compute stage1
#pragma unroll
    for (int i = 0; i < 4; ++i)
#pragma unroll
      for (int j = 0; j < 4; ++j) {
        acc[i][j] = mfma16h(a1[i], h1[j], acc[i][j]);
        acc[i][j] = mfma16h(a1[i], l1[j], acc[i][j]);
      }
  }

  // C/D layout: col = lane&15, row = (lane>>4)*4 + reg   [m89-verified]
  if (EPI == 0) {
    const int t = jg0 >> 10;  // 0:q 1:k 2:v  (uniform per block: 128 | 1024)
    _Float16* dst = (t == 0) ? qf : ((t == 1) ? kf : vv);
    float vld[4][4];
#pragma unroll
    for (int i = 0; i < 4; ++i)
#pragma unroll
      for (int r = 0; r < 4; ++r)
        vld[i][r] = (t == 0) ? 1.0f : valid[m0 + wm * 64 + i * 16 + lq * 4 + r];
#pragma unroll
    for (int jt = 0; jt < 4; ++jt) {
      int jcol = jg0 + wj * 64 + jt * 16 + lm;
      float bj = bias[jcol];
      int c = jcol & 1023, hd = c >> 6, d = c & 63;
#pragma unroll
      for (int i = 0; i < 4; ++i)
#pragma unroll
        for (int r = 0; r < 4; ++r) {
          int m = m0 + wm * 64 + i * 16 + lq * 4 + r;
          int b = m >> 12, n = m & 4095;
          float val = acc[i][jt][r] + bj;
          if (t <= 1) val = phi_f(val);
          if (t >= 1) val *= vld[i][r];
          dst[(((size_t)(b * H_ + hd) * N_ + n) << 6) + d] = (_Float16)val;
        }
    }
  } else {
#pragma unroll
    for (int jt = 0; jt < 4; ++jt) {
      int jcol = jg0 + wj * 64 + jt * 16 + lm;
      float bj = bias[jcol];
#pragma unroll
      for (int i = 0; i < 4; ++i)
#pragma unroll
        for (int r = 0; r < 4; ++r) {
          int m = m0 + wm * 64 + i * 16 + lq * 4 + r;
          outp[(size_t)m * C_ + jcol] = acc[i][jt][r] + bj;
        }
    }
  }
}

// ---------------- kv partials: kv[bh][d][e] = sum_n kf[bh][n][d]*v[bh][n][e]; z[bh][d] ----------------
__global__ __launch_bounds__(256) void kv_partial_k(
    const _Float16* __restrict__ kf, const _Float16* __restrict__ vv,
    float* __restrict__ kvp, float* __restrict__ zp) {
  const int bh = blockIdx.x, ch = blockIdx.y;
  const _Float16* kfr = kf + ((size_t)bh * N_ + ch * CHROWS) * 64;
  const _Float16* vr  = vv + ((size_t)bh * N_ + ch * CHROWS) * 64;
  __shared__ float ks[8][64], vs[8][64];
  const int tid = threadIdx.x;
  const int d0 = tid >> 2, eg = tid & 3;
  float acc[16] = {};
  float zacc = 0.f;
  for (int nb = 0; nb < CHROWS; nb += 8) {
    {
      int which = tid >> 7;
      int fl = tid & 127;
      int rr = fl >> 4, cc = (fl & 15) * 4;
      const _Float16* src = which ? vr : kfr;
      f16x4 t4 = *(const f16x4*)&src[(size_t)(nb + rr) * 64 + cc];
      float* d = which ? &vs[rr][cc] : &ks[rr][cc];
      d[0] = (float)t4[0]; d[1] = (float)t4[1];
      d[2] = (float)t4[2]; d[3] = (float)t4[3];
    }
    __syncthreads();
#pragma unroll
    for (int r = 0; r < 8; ++r) {
      float kd = ks[r][d0];
      if (eg == 0) zacc += kd;
#pragma unroll
      for (int i = 0; i < 16; ++i) acc[i] += kd * vs[r][eg * 16 + i];
    }
    __syncthreads();
  }
  size_t base = ((size_t)bh * NCH + ch) * 4096 + (size_t)d0 * 64 + eg * 16;
#pragma unroll
  for (int i = 0; i < 16; i += 4)
    *(float4*)&kvp[base + i] = make_float4(acc[i], acc[i+1], acc[i+2], acc[i+3]);
  if (eg == 0) zp[((size_t)bh * NCH + ch) * 64 + d0] = zacc;
}

__global__ __launch_bounds__(256) void kv_reduce_k(
    const float* __restrict__ kvp, const float* __restrict__ zp,
    float* __restrict__ kv, float* __restrict__ z) {
  const int bh = blockIdx.x, tid = threadIdx.x;
  for (int i = tid; i < 4096; i += 256) {
    float s = 0.f;
#pragma unroll
    for (int c = 0; c < NCH; ++c) s += kvp[((size_t)bh * NCH + c) * 4096 + i];
    kv[(size_t)bh * 4096 + i] = s;
  }
  if (tid < 64) {
    float s = 0.f;
#pragma unroll
    for (int c = 0; c < NCH; ++c) s += zp[((size_t)bh * NCH + c) * 64 + tid];
    z[bh * 64 + tid] = s;
  }
}

// ---------------- apply: Y[b,n,h*64+e] = (qf . kv) / max(qf . z, eps), fp16 out ----------------
__global__ __launch_bounds__(256) void attn_apply_k(
    const _Float16* __restrict__ qf, const float* __restrict__ kv,
    const float* __restrict__ z, _Float16* __restrict__ Y) {
  const int bh = blockIdx.x, nt = blockIdx.y;
  const int b = bh >> 4, hd = bh & 15;
  __shared__ float qs[128][65];
  __shared__ float kvs[64][68];
  __shared__ float zs[64];
  __shared__ float dens[128];
  const int tid = threadIdx.x;
  const _Float16* qrow = qf + ((size_t)bh * N_ + nt * 128) * 64;
#pragma unroll
  for (int i = 0; i < 4; ++i) {
    int fl = tid + i * 256;
    int d = fl >> 4, cc = (fl & 15) * 4;
    float4 t4 = *(const float4*)&kv[(size_t)bh * 4096 + d * 64 + cc];
    kvs[d][cc] = t4.x; kvs[d][cc+1] = t4.y; kvs[d][cc+2] = t4.z; kvs[d][cc+3] = t4.w;
  }
  if (tid < 64) zs[tid] = z[bh * 64 + tid];
#pragma unroll
  for (int i = 0; i < 4; ++i) {
    int fl = tid + i * 256;            // 0..1023 -> 128 rows x 8 chunks of 8
    int r = fl >> 3, cc = (fl & 7) * 8;
    f16x8 t8 = *(const f16x8*)&qrow[(size_t)r * 64 + cc];
#pragma unroll
    for (int j = 0; j < 8; ++j) qs[r][cc + j] = (float)t8[j];
  }
  __syncthreads();
  {
    int n = tid >> 1, half = tid & 1;
    float s = 0.f;
#pragma unroll
    for (int dd = 0; dd < 32; ++dd) {
      int d = half * 32 + dd;
      s += qs[n][d] * zs[d];
    }
    float other = __shfl_down(s, 1);
    if (half == 0) dens[n] = fmaxf(s + other, 1e-6f);
  }
  __syncthreads();
  const int ng = tid >> 3, eg = tid & 7;
  float acc[4][8] = {};
  for (int d = 0; d < 64; ++d) {
    float kvrow[8];
    *(float4*)&kvrow[0] = *(const float4*)&kvs[d][eg * 8];
    *(float4*)&kvrow[4] = *(const float4*)&kvs[d][eg * 8 + 4];
#pragma unroll
    for (int i = 0; i < 4; ++i) {
      float a = qs[ng * 4 + i][d];
#pragma unroll
      for (int j = 0; j < 8; ++j) acc[i][j] += a * kvrow[j];
    }
  }
#pragma unroll
  for (int i = 0; i < 4; ++i) {
    int nl = ng * 4 + i;
    int n = nt * 128 + nl;
    float inv = 1.0f / dens[nl];
    size_t off = ((size_t)b * N_ + n) * C_ + hd * 64 + eg * 8;
    f16x8 hv;
#pragma unroll
    for (int j = 0; j < 8; ++j) hv[j] = (_Float16)(acc[i][j] * inv);
    *(f16x8*)&Y[off] = hv;
  }
}

extern "C" void kernel_launch(void* const* d_in, const int* in_sizes, int n_in,
                              void* d_out, int out_size, void* d_ws, size_t ws_size,
                              hipStream_t stream) {
  const float* x      = (const float*)d_in[0];
  const float* W_qkv  = (const float*)d_in[1];
  const float* b_qkv  = (const float*)d_in[2];
  const float* W_out  = (const float*)d_in[3];
  const float* b_out  = (const float*)d_in[4];
  const void*  mask   = d_in[5];
  float* out = (float*)d_out;

  const size_t bhnd = (size_t)B_ * H_ * N_ * D_;   // 16,777,216
  _Float16* hs = (_Float16*)d_ws;
  _Float16* qf  = hs;                     // bhnd
  _Float16* kf  = qf + bhnd;              // bhnd
  _Float16* vv  = kf + bhnd;              // bhnd
  _Float16* Y   = vv + bhnd;              // bhnd
  _Float16* Xh  = Y + bhnd;               // bhnd
  _Float16* Wqh = Xh + bhnd;              // 3072*1024
  _Float16* Wql = Wqh + (size_t)3072 * 1024;
  _Float16* Woh = Wql + (size_t)3072 * 1024;   // 1024*1024
  _Float16* Wol = Woh + (size_t)1024 * 1024;
  float* tail = (float*)(Wol + (size_t)1024 * 1024);
  float* kvp = tail;                           // 64*8*4096
  float* zp  = kvp + (size_t)64 * NCH * 4096;
  float* kv  = zp + (size_t)64 * NCH * 64;
  float* z   = kv + (size_t)64 * 4096;
  float* valid = z + 64 * 64;
  int*   flag  = (int*)(valid + M_);

  mask_detect_k<<<1, 256, 0, stream>>>((const unsigned int*)mask, flag);
  mask_convert_k<<<M_ / 256, 256, 0, stream>>>(mask, flag, valid);
  conv_f16_k<<<(int)(bhnd / 4 / 256), 256, 0, stream>>>(x, Xh, (int)(bhnd / 4));
  split_f16_k<<<3072 * 1024 / 4 / 256, 256, 0, stream>>>(W_qkv, Wqh, Wql, 3072 * 1024 / 4);
  split_f16_k<<<1024 * 1024 / 4 / 256, 256, 0, stream>>>(W_out, Woh, Wol, 1024 * 1024 / 4);
  // fused QKV projection (j in [0,3072)) -> qf, kf, vv (fp16, [B,H,N,D])
  gemm_f16_k<0><<<dim3(M_ / 128, 24), 256, 0, stream>>>(
      Xh, Wqh, Wql, b_qkv, valid, qf, kf, vv, nullptr, 0);
  kv_partial_k<<<dim3(B_ * H_, NCH), 256, 0, stream>>>(kf, vv, kvp, zp);
  kv_reduce_k<<<B_ * H_, 256, 0, stream>>>(kvp, zp, kv, z);
  attn_apply_k<<<dim3(B_ * H_, N_ / 128), 256, 0, stream>>>(qf, kv, z, Y);
  // out-proj: A = Y (fp16 single), B = W_out split-2
  gemm_f16_k<1><<<dim3(M_ / 128, 8), 256, 0, stream>>>(
      Y, Woh, Wol, b_out, valid, nullptr, nullptr, nullptr, out, 0);
}